// Round 9
// baseline (146.323 us; speedup 1.0000x reference)
//
#include <hip/hip_runtime.h>
#include <hip/hip_bf16.h>

// Problem constants
#define T_ 8192
#define H_ 64
#define X_ 128
#define C_ 128   // chunks
#define L_ 64    // chunk length
#define MS 68    // matrix LDS row stride (floats)
#define VS1 68   // K1 vector buffer stride: 4 zero-pad + 64 t
#define VS2 132  // K2 scan buffer stride: 4 zero-pad + 128 c

// workspace float offsets
#define OFF_P   (T_ * H_)              // P[13][4096]: A^(2^s), s=0..12
#define OFF_HS  (OFF_P + 13 * 4096)    // hstart[128][64] row-major
#define OFF_G   (OFF_HS + C_ * H_)     // Ggt[64][4096]: (A^(i+1))^T

// ---------------------------------------------------------------------------
// acc[c] += sum_i m[i] * bv_i[c] : m = A-row over k..k+3, bv_i = B-row (k+i)
// ---------------------------------------------------------------------------
#define FMA_ROW(acc, m) \
  acc.x = fmaf(m.x, bv0.x, acc.x); acc.y = fmaf(m.x, bv0.y, acc.y); \
  acc.z = fmaf(m.x, bv0.z, acc.z); acc.w = fmaf(m.x, bv0.w, acc.w); \
  acc.x = fmaf(m.y, bv1.x, acc.x); acc.y = fmaf(m.y, bv1.y, acc.y); \
  acc.z = fmaf(m.y, bv1.z, acc.z); acc.w = fmaf(m.y, bv1.w, acc.w); \
  acc.x = fmaf(m.z, bv2.x, acc.x); acc.y = fmaf(m.z, bv2.y, acc.y); \
  acc.z = fmaf(m.z, bv2.z, acc.z); acc.w = fmaf(m.z, bv2.w, acc.w); \
  acc.x = fmaf(m.w, bv3.x, acc.x); acc.y = fmaf(m.w, bv3.y, acc.y); \
  acc.z = fmaf(m.w, bv3.z, acc.z); acc.w = fmaf(m.w, bv3.w, acc.w);

// ---------------------------------------------------------------------------
// mmt: Md = Ma * Mb (64x64, stride MS), 8r x 4t tiles on threads 0..127,
// rows r0+8j (conflict-free). Optional row-major global store. All threads
// must call (contains barriers). Md distinct from Ma, Mb.
// ---------------------------------------------------------------------------
__device__ __forceinline__ void mmt(const float* Ma, const float* Mb, float* Md,
                                    float* gout, int tid) {
    float4 a0{}, a1{}, a2{}, a3{}, a4{}, a5{}, a6{}, a7{};
    const int r0 = tid >> 4, t0 = (tid & 15) << 2;
    if (tid < 128) {
#pragma unroll 4
        for (int kk = 0; kk < 64; kk += 4) {
            const float4 bv0 = *(const float4*)(Mb + (kk + 0) * MS + t0);
            const float4 bv1 = *(const float4*)(Mb + (kk + 1) * MS + t0);
            const float4 bv2 = *(const float4*)(Mb + (kk + 2) * MS + t0);
            const float4 bv3 = *(const float4*)(Mb + (kk + 3) * MS + t0);
            float4 m;
            m = *(const float4*)(Ma + (r0 +  0) * MS + kk); FMA_ROW(a0, m)
            m = *(const float4*)(Ma + (r0 +  8) * MS + kk); FMA_ROW(a1, m)
            m = *(const float4*)(Ma + (r0 + 16) * MS + kk); FMA_ROW(a2, m)
            m = *(const float4*)(Ma + (r0 + 24) * MS + kk); FMA_ROW(a3, m)
            m = *(const float4*)(Ma + (r0 + 32) * MS + kk); FMA_ROW(a4, m)
            m = *(const float4*)(Ma + (r0 + 40) * MS + kk); FMA_ROW(a5, m)
            m = *(const float4*)(Ma + (r0 + 48) * MS + kk); FMA_ROW(a6, m)
            m = *(const float4*)(Ma + (r0 + 56) * MS + kk); FMA_ROW(a7, m)
        }
    }
    __syncthreads();
    if (tid < 128) {
        *(float4*)(Md + (r0 +  0) * MS + t0) = a0;
        *(float4*)(Md + (r0 +  8) * MS + t0) = a1;
        *(float4*)(Md + (r0 + 16) * MS + t0) = a2;
        *(float4*)(Md + (r0 + 24) * MS + t0) = a3;
        *(float4*)(Md + (r0 + 32) * MS + t0) = a4;
        *(float4*)(Md + (r0 + 40) * MS + t0) = a5;
        *(float4*)(Md + (r0 + 48) * MS + t0) = a6;
        *(float4*)(Md + (r0 + 56) * MS + t0) = a7;
        if (gout) {
            *(float4*)(gout + (r0 +  0) * H_ + t0) = a0;
            *(float4*)(gout + (r0 +  8) * H_ + t0) = a1;
            *(float4*)(gout + (r0 + 16) * H_ + t0) = a2;
            *(float4*)(gout + (r0 + 24) * H_ + t0) = a3;
            *(float4*)(gout + (r0 + 32) * H_ + t0) = a4;
            *(float4*)(gout + (r0 + 40) * H_ + t0) = a5;
            *(float4*)(gout + (r0 + 48) * H_ + t0) = a6;
            *(float4*)(gout + (r0 + 56) * H_ + t0) = a7;
        }
    }
    __syncthreads();
}

// ---------------------------------------------------------------------------
// pass_t: in-place doubling pass over V (row-major [64][VSTR], 4-float zero
// pad at col 0): V'[r][t] = V[r][t] + sum_k M[r][k] * V[k][t-DIST].
// 8r x 4t tiles on threads 0..8*TG-1 (TG t-groups). Reg-staged, 2 barriers.
// ---------------------------------------------------------------------------
template<int DIST, int TG, int VSTR>
__device__ __forceinline__ void pass_t(float* V, const float* M, int tid) {
    float4 a0{}, a1{}, a2{}, a3{}, a4{}, a5{}, a6{}, a7{};
    const int r0 = tid / TG, t0 = (tid % TG) << 2;
    const bool act = tid < 8 * TG;
    if (act) {
        a0 = *(const float4*)(V + (r0 +  0) * VSTR + 4 + t0);
        a1 = *(const float4*)(V + (r0 +  8) * VSTR + 4 + t0);
        a2 = *(const float4*)(V + (r0 + 16) * VSTR + 4 + t0);
        a3 = *(const float4*)(V + (r0 + 24) * VSTR + 4 + t0);
        a4 = *(const float4*)(V + (r0 + 32) * VSTR + 4 + t0);
        a5 = *(const float4*)(V + (r0 + 40) * VSTR + 4 + t0);
        a6 = *(const float4*)(V + (r0 + 48) * VSTR + 4 + t0);
        a7 = *(const float4*)(V + (r0 + 56) * VSTR + 4 + t0);
        if (DIST < 4 || t0 >= DIST) {
#pragma unroll 4
            for (int kk = 0; kk < 64; kk += 4) {
                float4 bv0, bv1, bv2, bv3;
                if (DIST >= 4) {
                    bv0 = *(const float4*)(V + (kk + 0) * VSTR + 4 + t0 - DIST);
                    bv1 = *(const float4*)(V + (kk + 1) * VSTR + 4 + t0 - DIST);
                    bv2 = *(const float4*)(V + (kk + 2) * VSTR + 4 + t0 - DIST);
                    bv3 = *(const float4*)(V + (kk + 3) * VSTR + 4 + t0 - DIST);
                } else {
#define SHIFT_BV(bv, KO) { \
    const float4 pr = *(const float4*)(V + (kk + KO) * VSTR + t0); \
    const float4 cu = *(const float4*)(V + (kk + KO) * VSTR + 4 + t0); \
    bv = (DIST == 1) ? make_float4(pr.w, cu.x, cu.y, cu.z) \
                     : make_float4(pr.z, pr.w, cu.x, cu.y); }
                    SHIFT_BV(bv0, 0) SHIFT_BV(bv1, 1) SHIFT_BV(bv2, 2) SHIFT_BV(bv3, 3)
#undef SHIFT_BV
                }
                float4 m;
                m = *(const float4*)(M + (r0 +  0) * MS + kk); FMA_ROW(a0, m)
                m = *(const float4*)(M + (r0 +  8) * MS + kk); FMA_ROW(a1, m)
                m = *(const float4*)(M + (r0 + 16) * MS + kk); FMA_ROW(a2, m)
                m = *(const float4*)(M + (r0 + 24) * MS + kk); FMA_ROW(a3, m)
                m = *(const float4*)(M + (r0 + 32) * MS + kk); FMA_ROW(a4, m)
                m = *(const float4*)(M + (r0 + 40) * MS + kk); FMA_ROW(a5, m)
                m = *(const float4*)(M + (r0 + 48) * MS + kk); FMA_ROW(a6, m)
                m = *(const float4*)(M + (r0 + 56) * MS + kk); FMA_ROW(a7, m)
            }
        }
    }
    __syncthreads();
    if (act) {
        *(float4*)(V + (r0 +  0) * VSTR + 4 + t0) = a0;
        *(float4*)(V + (r0 +  8) * VSTR + 4 + t0) = a1;
        *(float4*)(V + (r0 + 16) * VSTR + 4 + t0) = a2;
        *(float4*)(V + (r0 + 24) * VSTR + 4 + t0) = a3;
        *(float4*)(V + (r0 + 32) * VSTR + 4 + t0) = a4;
        *(float4*)(V + (r0 + 40) * VSTR + 4 + t0) = a5;
        *(float4*)(V + (r0 + 48) * VSTR + 4 + t0) = a6;
        *(float4*)(V + (r0 + 56) * VSTR + 4 + t0) = a7;
    }
    __syncthreads();
}

// ---------------------------------------------------------------------------
// K1: blocks 0..127: bproj of own chunk into V[e][4+t], then 6 doubling
//     passes interleaved with 5 local squarings -> chunk-local prefix d.
//     block 128: export P[s] = A^(2^s), s=0..12 (12 sequential squarings).
// ---------------------------------------------------------------------------
__global__ __launch_bounds__(256, 2) void k_chunks(
        const float* __restrict__ x, const float* __restrict__ A_raw,
        const float* __restrict__ B, const float* __restrict__ c,
        float* __restrict__ ws) {
    __shared__ __align__(16) float M1[H_ * MS];
    __shared__ __align__(16) float M2[H_ * MS];
    __shared__ __align__(16) float V[H_ * VS1];
    const int tid = threadIdx.x, lane = tid & 63, w = tid >> 6;
    float* d_pref = ws;
    float* P = ws + OFF_P;

    if (blockIdx.x == C_) {
        // ---- power block: P[s] = A^(2^s) ----
        for (int idx = tid; idx < H_ * H_; idx += 256) {
            const int r = idx >> 6, k = idx & 63;
            const float val = 0.1f * A_raw[idx] + ((r == k) ? 0.9f : 0.0f);
            M1[r * MS + k] = val;
            P[idx] = val;
        }
        __syncthreads();
        float* src = M1;
        float* dst = M2;
        for (int s = 1; s <= 12; ++s) {
            mmt(src, src, dst, P + s * 4096, tid);
            float* t = src; src = dst; dst = t;
        }
        return;
    }

    const int cid = blockIdx.x;
    // ---- b projection into V[e][4+t]: lane = e, wave w -> rows 16w..16w+15
    {
        const float cc = c[lane];
        float acc[16];
#pragma unroll
        for (int r = 0; r < 16; ++r) acc[r] = cc;
        const float* Brow = B + lane * X_;
        const int t0 = cid * L_ + w * 16;
        for (int kc = 0; kc < 4; ++kc) {
            const float4* bp = (const float4*)(Brow + kc * 32);
            float4 bb0=bp[0],bb1=bp[1],bb2=bp[2],bb3=bp[3],
                   bb4=bp[4],bb5=bp[5],bb6=bp[6],bb7=bp[7];
#pragma unroll
            for (int r = 0; r < 16; ++r) {
                const float4* x4 = (const float4*)(x + (size_t)(t0 + r) * X_ + kc * 32);
                float a = acc[r];
                float4 xv;
                xv = x4[0]; a=fmaf(bb0.x,xv.x,a); a=fmaf(bb0.y,xv.y,a); a=fmaf(bb0.z,xv.z,a); a=fmaf(bb0.w,xv.w,a);
                xv = x4[1]; a=fmaf(bb1.x,xv.x,a); a=fmaf(bb1.y,xv.y,a); a=fmaf(bb1.z,xv.z,a); a=fmaf(bb1.w,xv.w,a);
                xv = x4[2]; a=fmaf(bb2.x,xv.x,a); a=fmaf(bb2.y,xv.y,a); a=fmaf(bb2.z,xv.z,a); a=fmaf(bb2.w,xv.w,a);
                xv = x4[3]; a=fmaf(bb3.x,xv.x,a); a=fmaf(bb3.y,xv.y,a); a=fmaf(bb3.z,xv.z,a); a=fmaf(bb3.w,xv.w,a);
                xv = x4[4]; a=fmaf(bb4.x,xv.x,a); a=fmaf(bb4.y,xv.y,a); a=fmaf(bb4.z,xv.z,a); a=fmaf(bb4.w,xv.w,a);
                xv = x4[5]; a=fmaf(bb5.x,xv.x,a); a=fmaf(bb5.y,xv.y,a); a=fmaf(bb5.z,xv.z,a); a=fmaf(bb5.w,xv.w,a);
                xv = x4[6]; a=fmaf(bb6.x,xv.x,a); a=fmaf(bb6.y,xv.y,a); a=fmaf(bb6.z,xv.z,a); a=fmaf(bb6.w,xv.w,a);
                xv = x4[7]; a=fmaf(bb7.x,xv.x,a); a=fmaf(bb7.y,xv.y,a); a=fmaf(bb7.z,xv.z,a); a=fmaf(bb7.w,xv.w,a);
                acc[r] = a;
            }
        }
#pragma unroll
        for (int r = 0; r < 16; ++r)
            V[lane * VS1 + 4 + w * 16 + r] = acc[r];
    }
    // ---- zero pad + load A into M1 ----
    if (tid < 64) {
        V[tid * VS1 + 0] = 0.f; V[tid * VS1 + 1] = 0.f;
        V[tid * VS1 + 2] = 0.f; V[tid * VS1 + 3] = 0.f;
    }
    for (int idx = tid; idx < H_ * H_; idx += 256) {
        const int r = idx >> 6, k = idx & 63;
        M1[r * MS + k] = 0.1f * A_raw[idx] + ((r == k) ? 0.9f : 0.0f);
    }
    __syncthreads();

    // ---- 6 passes interleaved with 5 squarings ----
    pass_t<1,  16, VS1>(V, M1, tid);
    mmt(M1, M1, M2, nullptr, tid);     // M2 = A^2
    pass_t<2,  16, VS1>(V, M2, tid);
    mmt(M2, M2, M1, nullptr, tid);     // M1 = A^4
    pass_t<4,  16, VS1>(V, M1, tid);
    mmt(M1, M1, M2, nullptr, tid);     // M2 = A^8
    pass_t<8,  16, VS1>(V, M2, tid);
    mmt(M2, M2, M1, nullptr, tid);     // M1 = A^16
    pass_t<16, 16, VS1>(V, M1, tid);
    mmt(M1, M1, M2, nullptr, tid);     // M2 = A^32
    pass_t<32, 16, VS1>(V, M2, tid);

    // ---- transpose-write d (coalesced global float4) ----
    {
        const int ec = (tid & 15) * 4;
#pragma unroll
        for (int q = 0; q < 4; ++q) {
            const int t = (tid >> 4) + 16 * q;
            float4 o;
            o.x = V[(ec + 0) * VS1 + 4 + t];
            o.y = V[(ec + 1) * VS1 + 4 + t];
            o.z = V[(ec + 2) * VS1 + 4 + t];
            o.w = V[(ec + 3) * VS1 + 4 + t];
            *(float4*)(d_pref + ((size_t)(cid * L_ + t) * H_ + ec)) = o;
        }
    }
}

// ---------------------------------------------------------------------------
// K2: block 0: chunk-level doubling scan (7 passes, dist 1..64) over
//     u=[h0, v_0..v_126] col-major V2[e][4+c] with Q^(2^k) = P[6+k].
//     blocks 1..64: Ggt[n-1] = (A^n)^T by binary product over P[0..6].
// ---------------------------------------------------------------------------
__global__ __launch_bounds__(256, 2) void k_scan_g(
        const float* __restrict__ h0, float* __restrict__ ws) {
    __shared__ __align__(16) float smem[13056];  // 52224 B, phase-unioned
    const int tid = threadIdx.x;
    const float* d_pref = ws;
    const float* P = ws + OFF_P;
    float* hstart = ws + OFF_HS;
    float* Ggt = ws + OFF_G;

    if (blockIdx.x == 0) {
        float* V2 = smem;               // [64][VS2] = 8448 floats
        float* Mq = smem + H_ * VS2;    // [64][MS]  = 4352 floats
        for (int idx = tid; idx < C_ * H_; idx += 256) {
            const int cc = idx >> 6, e = idx & 63;
            const float val = (cc == 0)
                ? h0[e]
                : d_pref[(size_t)((cc - 1) * L_ + 63) * H_ + e];
            V2[e * VS2 + 4 + cc] = val;
        }
        if (tid < 64) {
            V2[tid * VS2 + 0] = 0.f; V2[tid * VS2 + 1] = 0.f;
            V2[tid * VS2 + 2] = 0.f; V2[tid * VS2 + 3] = 0.f;
        }
        __syncthreads();

#define SCAN_PASS(DIST, KK) \
        for (int idx = tid; idx < H_ * H_; idx += 256) \
            Mq[(idx >> 6) * MS + (idx & 63)] = P[(6 + KK) * 4096 + idx]; \
        __syncthreads(); \
        pass_t<DIST, 32, VS2>(V2, Mq, tid);
        SCAN_PASS(1, 0)
        SCAN_PASS(2, 1)
        SCAN_PASS(4, 2)
        SCAN_PASS(8, 3)
        SCAN_PASS(16, 4)
        SCAN_PASS(32, 5)
        SCAN_PASS(64, 6)
#undef SCAN_PASS

        // transpose-write hstart[c][e]
        const int ec = (tid & 15) * 4;
#pragma unroll
        for (int q = 0; q < 8; ++q) {
            const int cc = (tid >> 4) + 16 * q;
            float4 o;
            o.x = V2[(ec + 0) * VS2 + 4 + cc];
            o.y = V2[(ec + 1) * VS2 + 4 + cc];
            o.z = V2[(ec + 2) * VS2 + 4 + cc];
            o.w = V2[(ec + 3) * VS2 + 4 + cc];
            *(float4*)(hstart + cc * H_ + ec) = o;
        }
    } else {
        // G block: n = blockIdx.x in 1..64 ; Ggt[n-1] = (A^n)^T
        float* Mp = smem;
        float* Mf = smem + H_ * MS;
        float* Mo = smem + 2 * H_ * MS;
        const int n = blockIdx.x;
        const int j0 = __ffs(n) - 1;
        for (int idx = tid; idx < H_ * H_; idx += 256)
            Mp[(idx >> 6) * MS + (idx & 63)] = P[j0 * 4096 + idx];
        __syncthreads();
        for (int j = j0 + 1; j < 7; ++j) {
            if (!((n >> j) & 1)) continue;
            for (int idx = tid; idx < H_ * H_; idx += 256)
                Mf[(idx >> 6) * MS + (idx & 63)] = P[j * 4096 + idx];
            __syncthreads();
            mmt(Mf, Mp, Mo, nullptr, tid);   // Mo = A^(2^j) * product
            float* t = Mp; Mp = Mo; Mo = t;
        }
        // transposed store: Ggt[n-1][k][e] = A^n[e][k]
        for (int idx = tid; idx < H_ * H_; idx += 256)
            Ggt[(size_t)(n - 1) * 4096 + idx] = Mp[(idx & 63) * MS + (idx >> 6)];
    }
}

// ---------------------------------------------------------------------------
// K3: block i (0..63): out[c*64+i][e] = sum_k s_c[k]*Gt[k][e] + d[c][i][e]
// ---------------------------------------------------------------------------
__global__ __launch_bounds__(1024) void k_out(
        float* __restrict__ out, const float* __restrict__ ws) {
    __shared__ __align__(16) float S[C_ * MS];
    __shared__ __align__(16) float Gt[H_ * MS];
    const int tid = threadIdx.x;
    const float* d_pref = ws;
    const float* hstart = ws + OFF_HS;
    const float* Ggt = ws + OFF_G;
    const int i = blockIdx.x;

    for (int idx = tid; idx < C_ * H_; idx += 1024)
        S[(idx >> 6) * MS + (idx & 63)] = hstart[idx];
    for (int idx = tid; idx < H_ * H_; idx += 1024)
        Gt[(idx >> 6) * MS + (idx & 63)] = Ggt[(size_t)i * 4096 + idx];
    __syncthreads();

    const int c2 = tid >> 4, ec = (tid & 15) * 4;
#pragma unroll
    for (int h2 = 0; h2 < 2; ++h2) {
        const int cc = c2 + 64 * h2;
        const size_t base = (size_t)(cc * L_ + i) * H_ + ec;
        float4 acc = *(const float4*)(d_pref + base);
#pragma unroll 8
        for (int k = 0; k < 64; ++k) {
            const float m = S[cc * MS + k];
            const float4 g = *(const float4*)(Gt + k * MS + ec);
            acc.x = fmaf(m, g.x, acc.x);
            acc.y = fmaf(m, g.y, acc.y);
            acc.z = fmaf(m, g.z, acc.z);
            acc.w = fmaf(m, g.w, acc.w);
        }
        *(float4*)(out + base) = acc;
    }
}

extern "C" void kernel_launch(void* const* d_in, const int* in_sizes, int n_in,
                              void* d_out, int out_size, void* d_ws, size_t ws_size,
                              hipStream_t stream) {
    const float* x     = (const float*)d_in[0];  // [T, X]
    const float* h0    = (const float*)d_in[1];  // [H]
    const float* A_raw = (const float*)d_in[2];  // [H, H]
    const float* B     = (const float*)d_in[3];  // [H, X]
    const float* c     = (const float*)d_in[4];  // [H]
    float* out = (float*)d_out;                  // [T, H]
    float* ws  = (float*)d_ws;

    k_chunks<<<C_ + 1, 256, 0, stream>>>(x, A_raw, B, c, ws);
    k_scan_g<<<65,     256, 0, stream>>>(h0, ws);
    k_out   <<<64,     1024, 0, stream>>>(out, ws);
}

// Round 11
// 86.007 us; speedup vs baseline: 1.7013x; 1.7013x over previous
//
#include <hip/hip_runtime.h>
#include <hip/hip_bf16.h>

// Problem constants
#define T_ 8192
#define H_ 64
#define X_ 128
#define C_ 128   // chunks
#define L_ 64    // chunk length
#define PM 69    // fp32 matrix LDS stride (odd -> <=2-way b32 bank aliasing)
#define VS1c 97  // K1 V stride: 32 pad + 64 t + 1
#define PD1 32
#define VS2c 193 // K2 scan stride: 64 pad + 128 c + 1
#define PD2 64
#define MS 68    // K3 staging stride

// workspace float offsets
#define OFF_P   (T_ * H_)              // P[13][4096]: A^(2^s), s=0..12
#define OFF_HS  (OFF_P + 13 * 4096)    // hstart[128][64] row-major
#define OFF_G   (OFF_HS + C_ * H_)     // Ggt[64][4096]: (A^(i+1))^T

typedef short bf16x8 __attribute__((ext_vector_type(8)));
typedef float f32x4 __attribute__((ext_vector_type(4)));

// ---------------------------------------------------------------------------
// split8_3: read 8 fp32 (stride apart), split each into h+m+l bf16 (truncate).
// x = h + m + l with residual ~2^-24 |x| (fp32-equivalent representation).
// Subtractions are exact (Sterbenz: trunc keeps h within [x/2, 2x]).
// ---------------------------------------------------------------------------
__device__ __forceinline__ void split8_3(const float* p, int stride,
                                         bf16x8& hi, bf16x8& mi, bf16x8& lo) {
#pragma unroll
    for (int j = 0; j < 8; ++j) {
        const float x = p[j * stride];
        const unsigned u = __float_as_uint(x);
        hi[j] = (short)(u >> 16);
        const float r1 = x - __uint_as_float(u & 0xffff0000u);
        const unsigned u1 = __float_as_uint(r1);
        mi[j] = (short)(u1 >> 16);
        const float r2 = r1 - __uint_as_float(u1 & 0xffff0000u);
        lo[j] = (short)(__float_as_uint(r2) >> 16);
    }
}

// 6-term product: (ah+am+al)(bh+bm+bl) ~ hh + hm + mh + hl + lh + mm
#define MFMA6(ah, am, al, bh, bm, bl, acc) \
    acc = __builtin_amdgcn_mfma_f32_16x16x32_bf16(ah, bh, acc, 0, 0, 0); \
    acc = __builtin_amdgcn_mfma_f32_16x16x32_bf16(ah, bm, acc, 0, 0, 0); \
    acc = __builtin_amdgcn_mfma_f32_16x16x32_bf16(am, bh, acc, 0, 0, 0); \
    acc = __builtin_amdgcn_mfma_f32_16x16x32_bf16(ah, bl, acc, 0, 0, 0); \
    acc = __builtin_amdgcn_mfma_f32_16x16x32_bf16(al, bh, acc, 0, 0, 0); \
    acc = __builtin_amdgcn_mfma_f32_16x16x32_bf16(am, bm, acc, 0, 0, 0);

// ---------------------------------------------------------------------------
// mfma_mm: Md = Ma * Mb (64x64 fp32 in LDS, stride PM), optional row-major-64
// global store. 256 threads = 4 waves, wave w owns output rows 16w..16w+15.
// Ends with one __syncthreads (Md distinct from Ma/Mb).
// ---------------------------------------------------------------------------
__device__ __forceinline__ void mfma_mm(const float* Ma, const float* Mb,
                                        float* Md, float* gout, int tid) {
    const int lane = tid & 63, wv = tid >> 6;
    const int lr = lane & 15, lg = lane >> 4;
    const int R0 = wv * 16;
    bf16x8 ah0, am0, al0, ah1, am1, al1;
    split8_3(Ma + (R0 + lr) * PM + lg * 8, 1, ah0, am0, al0);
    split8_3(Ma + (R0 + lr) * PM + 32 + lg * 8, 1, ah1, am1, al1);
    f32x4 acc[4];
#pragma unroll
    for (int n = 0; n < 4; ++n) {
        acc[n] = (f32x4){0.f, 0.f, 0.f, 0.f};
        bf16x8 bh, bm, bl;
        split8_3(Mb + (lg * 8) * PM + 16 * n + lr, PM, bh, bm, bl);
        MFMA6(ah0, am0, al0, bh, bm, bl, acc[n])
        split8_3(Mb + (32 + lg * 8) * PM + 16 * n + lr, PM, bh, bm, bl);
        MFMA6(ah1, am1, al1, bh, bm, bl, acc[n])
    }
#pragma unroll
    for (int n = 0; n < 4; ++n)
#pragma unroll
        for (int q = 0; q < 4; ++q) {
            Md[(R0 + lg * 4 + q) * PM + 16 * n + lr] = acc[n][q];
            if (gout) gout[(R0 + lg * 4 + q) * H_ + 16 * n + lr] = acc[n][q];
        }
    __syncthreads();
}

// ---------------------------------------------------------------------------
// mfma_pass: in-place doubling pass V'[r][t] = V[r][t] + sum_k M[r][k]*V[k][t-DIST]
// V fp32 [64][VSTR] with PAD zero cols at left (absorbs all shifts). Identity
// term rides the fp32 accumulator init (no precision loss). NT n-tiles/wave.
// ---------------------------------------------------------------------------
template<int DIST, int PAD, int VSTR, int NT>
__device__ __forceinline__ void mfma_pass(float* V, const float* M, int tid) {
    const int lane = tid & 63, wv = tid >> 6;
    const int lr = lane & 15, lg = lane >> 4;
    const int R0 = wv * 16;
    bf16x8 ah0, am0, al0, ah1, am1, al1;
    split8_3(M + (R0 + lr) * PM + lg * 8, 1, ah0, am0, al0);
    split8_3(M + (R0 + lr) * PM + 32 + lg * 8, 1, ah1, am1, al1);
    f32x4 acc[NT];
#pragma unroll
    for (int n = 0; n < NT; ++n) {
#pragma unroll
        for (int q = 0; q < 4; ++q)
            acc[n][q] = V[(R0 + lg * 4 + q) * VSTR + PAD + 16 * n + lr];
        bf16x8 bh, bm, bl;
        split8_3(V + (lg * 8) * VSTR + PAD + 16 * n + lr - DIST, VSTR, bh, bm, bl);
        MFMA6(ah0, am0, al0, bh, bm, bl, acc[n])
        split8_3(V + (32 + lg * 8) * VSTR + PAD + 16 * n + lr - DIST, VSTR, bh, bm, bl);
        MFMA6(ah1, am1, al1, bh, bm, bl, acc[n])
    }
    __syncthreads();
#pragma unroll
    for (int n = 0; n < NT; ++n)
#pragma unroll
        for (int q = 0; q < 4; ++q)
            V[(R0 + lg * 4 + q) * VSTR + PAD + 16 * n + lr] = acc[n][q];
    __syncthreads();
}

// ---------------------------------------------------------------------------
// K1: blocks 0..127: bproj into V[e][PD1+t], 6 MFMA doubling passes + 5 local
//     MFMA squarings -> chunk-local prefix d. block 128: P[s]=A^(2^s), s=0..12.
// ---------------------------------------------------------------------------
__global__ __launch_bounds__(256) void k_chunks(
        const float* __restrict__ x, const float* __restrict__ A_raw,
        const float* __restrict__ B, const float* __restrict__ c,
        float* __restrict__ ws) {
    __shared__ __align__(16) float M1[H_ * PM];
    __shared__ __align__(16) float M2[H_ * PM];
    __shared__ __align__(16) float V[H_ * VS1c];
    const int tid = threadIdx.x, lane = tid & 63, w = tid >> 6;
    float* d_pref = ws;
    float* P = ws + OFF_P;

    if (blockIdx.x == C_) {
        // ---- power block: P[s] = A^(2^s) ----
        for (int idx = tid; idx < H_ * H_; idx += 256) {
            const int r = idx >> 6, k = idx & 63;
            const float val = 0.1f * A_raw[idx] + ((r == k) ? 0.9f : 0.0f);
            M1[r * PM + k] = val;
            P[idx] = val;
        }
        __syncthreads();
        float* src = M1;
        float* dst = M2;
        for (int s = 1; s <= 12; ++s) {
            mfma_mm(src, src, dst, P + s * 4096, tid);
            float* t = src; src = dst; dst = t;
        }
        return;
    }

    const int cid = blockIdx.x;
    // ---- b projection into V[e][PD1+t]: lane = e, wave w -> t rows 16w.. ----
    {
        const float cc = c[lane];
        float acc[16];
#pragma unroll
        for (int r = 0; r < 16; ++r) acc[r] = cc;
        const float* Brow = B + lane * X_;
        const int t0 = cid * L_ + w * 16;
        for (int kc = 0; kc < 4; ++kc) {
            const float4* bp = (const float4*)(Brow + kc * 32);
            float4 bb0=bp[0],bb1=bp[1],bb2=bp[2],bb3=bp[3],
                   bb4=bp[4],bb5=bp[5],bb6=bp[6],bb7=bp[7];
#pragma unroll
            for (int r = 0; r < 16; ++r) {
                const float4* x4 = (const float4*)(x + (size_t)(t0 + r) * X_ + kc * 32);
                float a = acc[r];
                float4 xv;
                xv = x4[0]; a=fmaf(bb0.x,xv.x,a); a=fmaf(bb0.y,xv.y,a); a=fmaf(bb0.z,xv.z,a); a=fmaf(bb0.w,xv.w,a);
                xv = x4[1]; a=fmaf(bb1.x,xv.x,a); a=fmaf(bb1.y,xv.y,a); a=fmaf(bb1.z,xv.z,a); a=fmaf(bb1.w,xv.w,a);
                xv = x4[2]; a=fmaf(bb2.x,xv.x,a); a=fmaf(bb2.y,xv.y,a); a=fmaf(bb2.z,xv.z,a); a=fmaf(bb2.w,xv.w,a);
                xv = x4[3]; a=fmaf(bb3.x,xv.x,a); a=fmaf(bb3.y,xv.y,a); a=fmaf(bb3.z,xv.z,a); a=fmaf(bb3.w,xv.w,a);
                xv = x4[4]; a=fmaf(bb4.x,xv.x,a); a=fmaf(bb4.y,xv.y,a); a=fmaf(bb4.z,xv.z,a); a=fmaf(bb4.w,xv.w,a);
                xv = x4[5]; a=fmaf(bb5.x,xv.x,a); a=fmaf(bb5.y,xv.y,a); a=fmaf(bb5.z,xv.z,a); a=fmaf(bb5.w,xv.w,a);
                xv = x4[6]; a=fmaf(bb6.x,xv.x,a); a=fmaf(bb6.y,xv.y,a); a=fmaf(bb6.z,xv.z,a); a=fmaf(bb6.w,xv.w,a);
                xv = x4[7]; a=fmaf(bb7.x,xv.x,a); a=fmaf(bb7.y,xv.y,a); a=fmaf(bb7.z,xv.z,a); a=fmaf(bb7.w,xv.w,a);
                acc[r] = a;
            }
        }
#pragma unroll
        for (int r = 0; r < 16; ++r)
            V[lane * VS1c + PD1 + w * 16 + r] = acc[r];
    }
    // ---- zero pad cols + load A into M1 ----
    for (int idx = tid; idx < H_ * PD1; idx += 256)
        V[(idx >> 5) * VS1c + (idx & 31)] = 0.f;
    for (int idx = tid; idx < H_ * H_; idx += 256) {
        const int r = idx >> 6, k = idx & 63;
        M1[r * PM + k] = 0.1f * A_raw[idx] + ((r == k) ? 0.9f : 0.0f);
    }
    __syncthreads();

    // ---- 6 MFMA passes interleaved with 5 MFMA squarings ----
    mfma_pass<1,  PD1, VS1c, 4>(V, M1, tid);
    mfma_mm(M1, M1, M2, nullptr, tid);     // M2 = A^2
    mfma_pass<2,  PD1, VS1c, 4>(V, M2, tid);
    mfma_mm(M2, M2, M1, nullptr, tid);     // M1 = A^4
    mfma_pass<4,  PD1, VS1c, 4>(V, M1, tid);
    mfma_mm(M1, M1, M2, nullptr, tid);     // M2 = A^8
    mfma_pass<8,  PD1, VS1c, 4>(V, M2, tid);
    mfma_mm(M2, M2, M1, nullptr, tid);     // M1 = A^16
    mfma_pass<16, PD1, VS1c, 4>(V, M1, tid);
    mfma_mm(M1, M1, M2, nullptr, tid);     // M2 = A^32
    mfma_pass<32, PD1, VS1c, 4>(V, M2, tid);

    // ---- transpose-write d (coalesced global float4) ----
    {
        const int ec = (tid & 15) * 4;
#pragma unroll
        for (int q = 0; q < 4; ++q) {
            const int t = (tid >> 4) + 16 * q;
            float4 o;
            o.x = V[(ec + 0) * VS1c + PD1 + t];
            o.y = V[(ec + 1) * VS1c + PD1 + t];
            o.z = V[(ec + 2) * VS1c + PD1 + t];
            o.w = V[(ec + 3) * VS1c + PD1 + t];
            *(float4*)(d_pref + ((size_t)(cid * L_ + t) * H_ + ec)) = o;
        }
    }
}

// ---------------------------------------------------------------------------
// K2: block 0: chunk-level MFMA doubling scan (7 passes, dist 1..64) over
//     u=[h0, v_0..v_126] in V2[e][PD2+c] with Q^(2^k) = P[6+k].
//     blocks 1..64: Ggt[n-1] = (A^n)^T by binary MFMA product over P[0..6].
// ---------------------------------------------------------------------------
__global__ __launch_bounds__(256) void k_scan_g(
        const float* __restrict__ h0, float* __restrict__ ws) {
    __shared__ __align__(16) float smem[H_ * VS2c + H_ * PM];  // 67 KB union
    const int tid = threadIdx.x;
    const float* d_pref = ws;
    const float* P = ws + OFF_P;
    float* hstart = ws + OFF_HS;
    float* Ggt = ws + OFF_G;

    if (blockIdx.x == 0) {
        float* V2 = smem;                 // [64][VS2c]
        float* Mq = smem + H_ * VS2c;     // [64][PM]
        for (int idx = tid; idx < C_ * H_; idx += 256) {
            const int cc = idx >> 6, e = idx & 63;
            const float val = (cc == 0)
                ? h0[e]
                : d_pref[(size_t)((cc - 1) * L_ + 63) * H_ + e];
            V2[e * VS2c + PD2 + cc] = val;
        }
        for (int idx = tid; idx < H_ * PD2; idx += 256)
            V2[(idx >> 6) * VS2c + (idx & 63)] = 0.f;
        __syncthreads();

#define SCAN_PASS(DIST, KK) \
        for (int idx = tid; idx < H_ * H_; idx += 256) \
            Mq[(idx >> 6) * PM + (idx & 63)] = P[(6 + KK) * 4096 + idx]; \
        __syncthreads(); \
        mfma_pass<DIST, PD2, VS2c, 8>(V2, Mq, tid);
        SCAN_PASS(1, 0)
        SCAN_PASS(2, 1)
        SCAN_PASS(4, 2)
        SCAN_PASS(8, 3)
        SCAN_PASS(16, 4)
        SCAN_PASS(32, 5)
        SCAN_PASS(64, 6)
#undef SCAN_PASS

        // transpose-write hstart[c][e]
        const int ec = (tid & 15) * 4;
#pragma unroll
        for (int q = 0; q < 8; ++q) {
            const int cc = (tid >> 4) + 16 * q;
            float4 o;
            o.x = V2[(ec + 0) * VS2c + PD2 + cc];
            o.y = V2[(ec + 1) * VS2c + PD2 + cc];
            o.z = V2[(ec + 2) * VS2c + PD2 + cc];
            o.w = V2[(ec + 3) * VS2c + PD2 + cc];
            *(float4*)(hstart + cc * H_ + ec) = o;
        }
    } else {
        // G block: n = blockIdx.x in 1..64 ; Ggt[n-1] = (A^n)^T
        float* Mp = smem;
        float* Mf = smem + H_ * PM;
        float* Mo = smem + 2 * H_ * PM;
        const int n = blockIdx.x;
        const int j0 = __ffs(n) - 1;
        for (int idx = tid; idx < H_ * H_; idx += 256)
            Mp[(idx >> 6) * PM + (idx & 63)] = P[j0 * 4096 + idx];
        __syncthreads();
        for (int j = j0 + 1; j < 7; ++j) {
            if (!((n >> j) & 1)) continue;
            for (int idx = tid; idx < H_ * H_; idx += 256)
                Mf[(idx >> 6) * PM + (idx & 63)] = P[j * 4096 + idx];
            __syncthreads();
            mfma_mm(Mf, Mp, Mo, nullptr, tid);   // Mo = A^(2^j) * product
            float* t = Mp; Mp = Mo; Mo = t;
        }
        // transposed store: Ggt[n-1][k][e] = A^n[e][k]
        for (int idx = tid; idx < H_ * H_; idx += 256)
            Ggt[(size_t)(n - 1) * 4096 + idx] = Mp[(idx & 63) * PM + (idx >> 6)];
    }
}

// ---------------------------------------------------------------------------
// K3: block i (0..63): out[c*64+i][e] = sum_k s_c[k]*Gt[k][e] + d[c][i][e]
// ---------------------------------------------------------------------------
__global__ __launch_bounds__(1024) void k_out(
        float* __restrict__ out, const float* __restrict__ ws) {
    __shared__ __align__(16) float S[C_ * MS];
    __shared__ __align__(16) float Gt[H_ * MS];
    const int tid = threadIdx.x;
    const float* d_pref = ws;
    const float* hstart = ws + OFF_HS;
    const float* Ggt = ws + OFF_G;
    const int i = blockIdx.x;

    for (int idx = tid; idx < C_ * H_; idx += 1024)
        S[(idx >> 6) * MS + (idx & 63)] = hstart[idx];
    for (int idx = tid; idx < H_ * H_; idx += 1024)
        Gt[(idx >> 6) * MS + (idx & 63)] = Ggt[(size_t)i * 4096 + idx];
    __syncthreads();

    const int c2 = tid >> 4, ec = (tid & 15) * 4;
#pragma unroll
    for (int h2 = 0; h2 < 2; ++h2) {
        const int cc = c2 + 64 * h2;
        const size_t base = (size_t)(cc * L_ + i) * H_ + ec;
        float4 acc = *(const float4*)(d_pref + base);
#pragma unroll 8
        for (int k = 0; k < 64; ++k) {
            const float m = S[cc * MS + k];
            const float4 g = *(const float4*)(Gt + k * MS + ec);
            acc.x = fmaf(m, g.x, acc.x);
            acc.y = fmaf(m, g.y, acc.y);
            acc.z = fmaf(m, g.z, acc.z);
            acc.w = fmaf(m, g.w, acc.w);
        }
        *(float4*)(out + base) = acc;
    }
}

extern "C" void kernel_launch(void* const* d_in, const int* in_sizes, int n_in,
                              void* d_out, int out_size, void* d_ws, size_t ws_size,
                              hipStream_t stream) {
    const float* x     = (const float*)d_in[0];  // [T, X]
    const float* h0    = (const float*)d_in[1];  // [H]
    const float* A_raw = (const float*)d_in[2];  // [H, H]
    const float* B     = (const float*)d_in[3];  // [H, X]
    const float* c     = (const float*)d_in[4];  // [H]
    float* out = (float*)d_out;                  // [T, H]
    float* ws  = (float*)d_ws;

    k_chunks<<<C_ + 1, 256, 0, stream>>>(x, A_raw, B, c, ws);
    k_scan_g<<<65,     256, 0, stream>>>(h0, ws);
    k_out   <<<64,     1024, 0, stream>>>(out, ws);
}